// Round 1
// baseline (117.076 us; speedup 1.0000x reference)
//
#include <hip/hip_runtime.h>
#include <hip/hip_bf16.h>
#include <stdint.h>

typedef unsigned short ushort_t;
typedef __bf16 bf16x8 __attribute__((ext_vector_type(8)));
typedef float f32x4 __attribute__((ext_vector_type(4)));

#define T_TOK 8192
#define H_DIM 1024
#define E_EXP 8
#define BM 256
#define BN 256
#define BK 64
#define NKT (H_DIM / BK)               // 16
#define NITER (NKT / 2)                // 8
#define MT_MAX (T_TOK / BM)            // 32
#define NT_N (H_DIM / BN)              // 4
#define WG_PER_E (MT_MAX * NT_N)       // 128
#define NWG_G (E_EXP * WG_PER_E)       // 1024

#define CNT_STRIDE 64
#define RTOK 32
#define RBLOCKS (T_TOK / RTOK)

static __device__ __forceinline__ ushort_t f2bf(float f) {
  union { float f; uint32_t u; } c; c.f = f;
  uint32_t u = c.u;
  uint32_t r = u + 0x7FFFu + ((u >> 16) & 1u);  // RNE
  return (ushort_t)(r >> 16);
}

// ---------------- Router: logits -> softmax -> top2 -> gather lists ---------
__global__ __launch_bounds__(256) void router_kernel(
    const float* __restrict__ x, const float* __restrict__ gw,
    const float* __restrict__ gb,
    float* __restrict__ out_idx, float* __restrict__ out_probs,
    ushort_t* __restrict__ x_bf, int* __restrict__ counts,
    int* __restrict__ tok, float* __restrict__ wts, int* __restrict__ slotmap)
{
  __shared__ int   sm_eid[RTOK * 2];
  __shared__ float sm_wt[RTOK * 2];
  __shared__ int   lcnt[E_EXP], lbase[E_EXP], lpos[E_EXP];

  const int tid = threadIdx.x;
  const int wave = tid >> 6, l = tid & 63;
  if (tid < E_EXP) { lcnt[tid] = 0; lpos[tid] = 0; }
  __syncthreads();

  const int t0 = blockIdx.x * RTOK;
  for (int it = 0; it < RTOK / 4; it++) {
    const int lt = wave * (RTOK / 4) + it;
    const int t = t0 + lt;
    const float* xt = x + (size_t)t * H_DIM;
    float acc[E_EXP];
#pragma unroll
    for (int e = 0; e < E_EXP; e++) acc[e] = 0.f;
#pragma unroll
    for (int i = 0; i < 4; i++) {
      const int h = (i * 64 + l) * 4;
      const float4 xv = *reinterpret_cast<const float4*>(xt + h);
      ushort4 b;
      b.x = f2bf(xv.x); b.y = f2bf(xv.y); b.z = f2bf(xv.z); b.w = f2bf(xv.w);
      *reinterpret_cast<ushort4*>(x_bf + (size_t)t * H_DIM + h) = b;
#pragma unroll
      for (int e = 0; e < E_EXP; e++) {
        const float4 g = *reinterpret_cast<const float4*>(gw + e * H_DIM + h);
        acc[e] += xv.x * g.x + xv.y * g.y + xv.z * g.z + xv.w * g.w;
      }
    }
#pragma unroll
    for (int e = 0; e < E_EXP; e++) {
      float v = acc[e];
#pragma unroll
      for (int off = 32; off; off >>= 1) v += __shfl_xor(v, off);
      acc[e] = v;
    }
    if (l == 0) {
      float lg[E_EXP], pb[E_EXP];
      float m = -1e30f;
#pragma unroll
      for (int e = 0; e < E_EXP; e++) { lg[e] = acc[e] + gb[e]; m = fmaxf(m, lg[e]); }
      float s = 0.f;
#pragma unroll
      for (int e = 0; e < E_EXP; e++) { pb[e] = expf(lg[e] - m); s += pb[e]; }
      const float inv = 1.f / s;
#pragma unroll
      for (int e = 0; e < E_EXP; e++) {
        pb[e] *= inv;
        out_probs[(size_t)t * E_EXP + e] = pb[e];
      }
      int i0 = 0; float p0 = pb[0];
#pragma unroll
      for (int e = 1; e < E_EXP; e++) if (pb[e] > p0) { p0 = pb[e]; i0 = e; }
      int i1 = -1; float p1 = -1.f;
#pragma unroll
      for (int e = 0; e < E_EXP; e++) if (e != i0 && pb[e] > p1) { p1 = pb[e]; i1 = e; }
      out_idx[(size_t)t * 2 + 0] = (float)i0;
      out_idx[(size_t)t * 2 + 1] = (float)i1;
      const float rn = 1.f / (p0 + p1);
      sm_eid[lt * 2 + 0] = i0; sm_wt[lt * 2 + 0] = p0 * rn;
      sm_eid[lt * 2 + 1] = i1; sm_wt[lt * 2 + 1] = p1 * rn;
    }
  }
  __syncthreads();

  if (tid < RTOK * 2) atomicAdd(&lcnt[sm_eid[tid]], 1);
  __syncthreads();
  if (tid < E_EXP) lbase[tid] = atomicAdd(&counts[tid * CNT_STRIDE], lcnt[tid]);
  __syncthreads();
  if (tid < RTOK * 2) {
    const int e = sm_eid[tid];
    const int p = lbase[e] + atomicAdd(&lpos[e], 1);
    tok[e * T_TOK + p] = t0 + (tid >> 1);
    wts[e * T_TOK + p] = sm_wt[tid];
    slotmap[(t0 + (tid >> 1)) * 2 + (tid & 1)] = e * T_TOK + p;
  }
}

// ------------- expert_w [E,K,N] f32 -> wT [E,N,K] bf16 ----------------------
__global__ __launch_bounds__(256) void transpose_convert(
    const float* __restrict__ w, ushort_t* __restrict__ wT)
{
  __shared__ float tile[32][33];
  const int e = blockIdx.z;
  const float* we = w + (size_t)e * H_DIM * H_DIM;
  ushort_t* wTe = wT + (size_t)e * H_DIM * H_DIM;
  const int n0 = blockIdx.x * 32, k0 = blockIdx.y * 32;
  const int tx = threadIdx.x & 31, ty = threadIdx.x >> 5;  // 32 x 8
#pragma unroll
  for (int i = 0; i < 4; i++)
    tile[ty + 8 * i][tx] = we[(size_t)(k0 + ty + 8 * i) * H_DIM + n0 + tx];
  __syncthreads();
#pragma unroll
  for (int i = 0; i < 4; i++)
    wTe[(size_t)(n0 + ty + 8 * i) * H_DIM + k0 + tx] = f2bf(tile[tx][ty + 8 * i]);
}

// ------------------- Gathered grouped GEMM (per expert) ---------------------
// 256x256 tile, 8 waves (2Mx4N), 8-phase counted-vmcnt schedule (T3+T4),
// chunk-XOR LDS swizzle (T2, both-sides), setprio around MFMA (T5).
// LDS: A/B each [2 buf][2 K-half][256 rows x 4 chunks of 16B] = 128 KiB.
// Staging: per phase 1 half-tile = 2 x global_load_lds(16B)/thread.
// vmcnt(6) only at phases 4 and 8 (3 half-tiles in flight); drain on last iter.
#define GLDS16(gp, lp)                                                         \
  __builtin_amdgcn_global_load_lds(                                            \
      (const __attribute__((address_space(1))) void*)(gp),                     \
      (__attribute__((address_space(3))) void*)(lp), 16, 0, 0)

#define WAITV6() asm volatile("s_waitcnt vmcnt(6)" ::: "memory")
#define WAITV0() asm volatile("s_waitcnt vmcnt(0)" ::: "memory")
#define LGKM0()                                                                \
  do {                                                                         \
    asm volatile("s_waitcnt lgkmcnt(0)" ::: "memory");                         \
    __builtin_amdgcn_sched_barrier(0);                                         \
  } while (0)
#define BAR()                                                                  \
  do {                                                                         \
    __builtin_amdgcn_sched_barrier(0);                                         \
    __builtin_amdgcn_s_barrier();                                              \
    __builtin_amdgcn_sched_barrier(0);                                         \
  } while (0)

__global__ __launch_bounds__(512, 2) void moe_gemm(
    const ushort_t* __restrict__ x_bf, const ushort_t* __restrict__ wT,
    const float* __restrict__ bias, const int* __restrict__ counts,
    const int* __restrict__ tok, const float* __restrict__ wts,
    ushort_t* __restrict__ y)
{
  // Expert-pinned XCD swizzle: XCD i runs expert i's 128 wgids (wT fits L2).
  const int lin  = blockIdx.x;
  const int wgid = (lin & 7) * WG_PER_E + (lin >> 3);
  const int e    = wgid >> 7;
  const int rem  = wgid & (WG_PER_E - 1);
  const int mt   = rem >> 2;          // 0..31
  const int nt   = rem & 3;           // 0..3
  const int n_e  = counts[e * CNT_STRIDE];
  if (mt * BM >= n_e) return;

  // [buf][khalf][256 rows * 32 elems] ; one K-half = 16 KiB, lane-linear dest.
  __shared__ __align__(16) ushort_t As[2][2][BM * 32];
  __shared__ __align__(16) ushort_t Bs[2][2][BN * 32];
  __shared__ int stok[BM];
  __shared__ float swt[BM];

  const int tid = threadIdx.x;
  if (tid < BM) {
    int slot = mt * BM + tid;
    if (slot >= n_e) slot = n_e - 1;  // clamp: garbage rows masked on store
    stok[tid] = tok[e * T_TOK + slot];
    swt[tid] = wts[e * T_TOK + slot];
  }
  __syncthreads();

  // Staging: K-half of a tile = 256 rows x 4 chunks(16B) = 1024 chunks
  //        = 512 threads x 2. Phys chunk p = tid + i*512 -> row p>>2, slot p&3.
  // Logical chunk-in-half = slot ^ ((row>>1)&3), applied on the SOURCE addr.
  const int r0 = tid >> 2;                         // 0..127
  const int cp = (tid & 3) ^ ((tid >> 3) & 3);     // logical chunk-in-half
  const ushort_t* wTe = wT + (size_t)e * H_DIM * H_DIM;
  const ushort_t* aP0 = x_bf + (size_t)stok[r0] * H_DIM + cp * 8;
  const ushort_t* aP1 = x_bf + (size_t)stok[r0 + 128] * H_DIM + cp * 8;
  const ushort_t* bP0 = wTe + (size_t)(nt * BN + r0) * H_DIM + cp * 8;
  const ushort_t* bP1 = wTe + (size_t)(nt * BN + r0 + 128) * H_DIM + cp * 8;
  const int d0 = tid * 8;
  const int d1 = (tid + 512) * 8;

#define STAGE_A(t, kh, buf)                                                    \
  do {                                                                         \
    GLDS16(aP0 + (t) * BK + (kh) * 32, &As[(buf)][(kh)][d0]);                  \
    GLDS16(aP1 + (t) * BK + (kh) * 32, &As[(buf)][(kh)][d1]);                  \
  } while (0)
#define STAGE_B(t, kh, buf)                                                    \
  do {                                                                         \
    GLDS16(bP0 + (t) * BK + (kh) * 32, &Bs[(buf)][(kh)][d0]);                  \
    GLDS16(bP1 + (t) * BK + (kh) * 32, &Bs[(buf)][(kh)][d1]);                  \
  } while (0)

  const int l = tid & 63;
  const int wid = tid >> 6;
  const int wm = wid >> 2, wn = wid & 3;      // 2x4 waves over 256x256
  const int fr = l & 15;
  const int g = l >> 4;
  const int sl = g ^ ((l >> 1) & 3);          // swizzled slot-in-half
  const int arow0 = wm * 128 + fr;
  const int brow0 = wn * 64 + fr;

  bf16x8 af[8], bv[2];
  f32x4 acc[8][4] = {};

#define READ_A(buf, kk)                                                        \
  do {                                                                         \
    _Pragma("unroll") for (int mi = 0; mi < 8; mi++)                           \
        af[mi] = *reinterpret_cast<const bf16x8*>(                             \
            &As[(buf)][(kk)][(arow0 + mi * 16) * 32 + sl * 8]);                \
  } while (0)
#define READ_B(buf, kk, nh)                                                    \
  do {                                                                         \
    _Pragma("unroll") for (int j = 0; j < 2; j++)                              \
        bv[j] = *reinterpret_cast<const bf16x8*>(                              \
            &Bs[(buf)][(kk)][(brow0 + ((nh) * 2 + j) * 16) * 32 + sl * 8]);    \
  } while (0)
#define MFMA16(nh)                                                             \
  do {                                                                         \
    __builtin_amdgcn_s_setprio(1);                                             \
    _Pragma("unroll") for (int mi = 0; mi < 8; mi++)                           \
        _Pragma("unroll") for (int j = 0; j < 2; j++)                          \
            acc[mi][(nh) * 2 + j] = __builtin_amdgcn_mfma_f32_16x16x32_bf16(   \
                af[mi], bv[j], acc[mi][(nh) * 2 + j], 0, 0, 0);                \
    __builtin_amdgcn_s_setprio(0);                                             \
  } while (0)

  // 8 phases / iteration (2 K-tiles). Stage targets are regions whose last
  // consumer read completed >=1 barrier earlier; vmcnt(6)+barrier at p3/p7
  // confirm the next K-tile landed (across all waves) before its first read.
#define ITER_BODY(TT, MORE)                                                    \
  do {                                                                         \
    /* p0: buf0 kk0 nh0 | stage B-Kh1(t+1)->buf1 */                            \
    READ_A(0, 0); READ_B(0, 0, 0);                                             \
    STAGE_B((TT) + 1, 1, 1);                                                   \
    BAR(); LGKM0(); MFMA16(0); BAR();                                          \
    /* p1: buf0 kk0 nh1 | stage A-Kh0(t+2)->buf0 */                            \
    READ_B(0, 0, 1);                                                           \
    if (MORE) STAGE_A((TT) + 2, 0, 0);                                         \
    BAR(); LGKM0(); MFMA16(1); BAR();                                          \
    /* p2: buf0 kk1 nh0 | stage B-Kh0(t+2)->buf0 */                            \
    READ_A(0, 1); READ_B(0, 1, 0);                                             \
    if (MORE) STAGE_B((TT) + 2, 0, 0);                                         \
    BAR(); LGKM0(); MFMA16(0); BAR();                                          \
    /* p3: buf0 kk1 nh1 | stage A-Kh1(t+2)->buf0 | CHECKPOINT (tile t+1) */    \
    READ_B(0, 1, 1);                                                           \
    if (MORE) { STAGE_A((TT) + 2, 1, 0); WAITV6(); } else { WAITV0(); }        \
    BAR(); LGKM0(); MFMA16(1); BAR();                                          \
    /* p4: buf1 kk0 nh0 | stage B-Kh1(t+2)->buf0 */                            \
    READ_A(1, 0); READ_B(1, 0, 0);                                             \
    if (MORE) STAGE_B((TT) + 2, 1, 0);                                         \
    BAR(); LGKM0(); MFMA16(0); BAR();                                          \
    /* p5: buf1 kk0 nh1 | stage A-Kh0(t+3)->buf1 */                            \
    READ_B(1, 0, 1);                                                           \
    if (MORE) STAGE_A((TT) + 3, 0, 1);                                         \
    BAR(); LGKM0(); MFMA16(1); BAR();                                          \
    /* p6: buf1 kk1 nh0 | stage B-Kh0(t+3)->buf1 */                            \
    READ_A(1, 1); READ_B(1, 1, 0);                                             \
    if (MORE) STAGE_B((TT) + 3, 0, 1);                                         \
    BAR(); LGKM0(); MFMA16(0); BAR();                                          \
    /* p7: buf1 kk1 nh1 | stage A-Kh1(t+3)->buf1 | CHECKPOINT (tile t+2) */    \
    READ_B(1, 1, 1);                                                           \
    if (MORE) { STAGE_A((TT) + 3, 1, 1); WAITV6(); }                           \
    BAR(); LGKM0(); MFMA16(1); BAR();                                          \
  } while (0)

  // Prologue: tile0 fully (4 halves), tile1 minus its B-Kh1 (3 halves);
  // 14 loads issued, vmcnt(6) -> oldest 8 (= tile0) landed.
  STAGE_A(0, 0, 0); STAGE_B(0, 0, 0); STAGE_A(0, 1, 0); STAGE_B(0, 1, 0);
  STAGE_A(1, 0, 1); STAGE_B(1, 0, 1); STAGE_A(1, 1, 1);
  WAITV6();
  BAR();

#pragma unroll 1
  for (int it = 0; it < NITER - 1; ++it) {
    const int t = 2 * it;
    ITER_BODY(t, 1);
  }
  {
    const int t = 2 * (NITER - 1);
    ITER_BODY(t, 0);
  }

  // Epilogue: C/D layout col=lane&15, row=(lane>>4)*4+reg.
  ushort_t* ye = y + ((size_t)e * T_TOK + (size_t)mt * BM) * H_DIM;
  float bias4[4];
#pragma unroll
  for (int ni = 0; ni < 4; ni++)
    bias4[ni] = bias[e * H_DIM + nt * BN + wn * 64 + ni * 16 + fr];
#pragma unroll
  for (int mi = 0; mi < 8; mi++) {
    const int rr0 = wm * 128 + mi * 16 + g * 4;
#pragma unroll
    for (int r = 0; r < 4; r++) {
      const int row = rr0 + r;
      if (mt * BM + row < n_e) {
        const float wgt = swt[row];
#pragma unroll
        for (int ni = 0; ni < 4; ni++) {
          const int n = nt * BN + wn * 64 + ni * 16 + fr;
          ye[(size_t)row * H_DIM + n] = f2bf(wgt * (acc[mi][ni][r] + bias4[ni]));
        }
      }
    }
  }
}

// ------------- combine: out[t] = y[slot0(t)] + y[slot1(t)] ------------------
__global__ __launch_bounds__(256) void combine_kernel(
    const ushort_t* __restrict__ y, const int* __restrict__ slotmap,
    float* __restrict__ out)
{
  const int t = blockIdx.x;
  const int s0 = slotmap[t * 2 + 0];
  const int s1 = slotmap[t * 2 + 1];
  const ushort_t* r0 = y + (size_t)s0 * H_DIM;
  const ushort_t* r1 = y + (size_t)s1 * H_DIM;
  float* o = out + (size_t)t * H_DIM;
  const int h = threadIdx.x * 4;
  const ushort4 u0 = *reinterpret_cast<const ushort4*>(r0 + h);
  const ushort4 u1 = *reinterpret_cast<const ushort4*>(r1 + h);
  float4 v;
  union { uint32_t u; float f; } c;
  c.u = (uint32_t)u0.x << 16; v.x = c.f; c.u = (uint32_t)u1.x << 16; v.x += c.f;
  c.u = (uint32_t)u0.y << 16; v.y = c.f; c.u = (uint32_t)u1.y << 16; v.y += c.f;
  c.u = (uint32_t)u0.z << 16; v.z = c.f; c.u = (uint32_t)u1.z << 16; v.z += c.f;
  c.u = (uint32_t)u0.w << 16; v.w = c.f; c.u = (uint32_t)u1.w << 16; v.w += c.f;
  *reinterpret_cast<float4*>(o + h) = v;
}

extern "C" void kernel_launch(void* const* d_in, const int* in_sizes, int n_in,
                              void* d_out, int out_size, void* d_ws, size_t ws_size,
                              hipStream_t stream)
{
  const float* x  = (const float*)d_in[0];
  const float* gw = (const float*)d_in[1];
  const float* gb = (const float*)d_in[2];
  const float* ew = (const float*)d_in[3];
  const float* eb = (const float*)d_in[4];

  float* out = (float*)d_out;
  float* out_final = out;                                  // [T,H] f32
  float* out_idx   = out + (size_t)T_TOK * H_DIM;          // [T,2] as f32
  float* out_probs = out_idx + (size_t)T_TOK * 2;          // [T,E] f32

  char* ws = (char*)d_ws;
  size_t off = 0;
  int*      counts  = (int*)(ws + off); off += 4096;
  int*      tok     = (int*)(ws + off); off += (size_t)E_EXP * T_TOK * 4;
  float*    wts     = (float*)(ws + off); off += (size_t)E_EXP * T_TOK * 4;
  int*      slotmap = (int*)(ws + off); off += (size_t)T_TOK * 2 * 4;
  ushort_t* x_bf    = (ushort_t*)(ws + off); off += (size_t)T_TOK * H_DIM * 2;
  ushort_t* wT      = (ushort_t*)(ws + off); off += (size_t)E_EXP * H_DIM * H_DIM * 2;
  ushort_t* y       = (ushort_t*)(ws + off); off += (size_t)E_EXP * T_TOK * H_DIM * 2;
  // total ~66.6 MB of d_ws

  hipMemsetAsync(counts, 0, 4096, stream);

  transpose_convert<<<dim3(H_DIM / 32, H_DIM / 32, E_EXP), 256, 0, stream>>>(ew, wT);
  router_kernel<<<RBLOCKS, 256, 0, stream>>>(x, gw, gb, out_idx, out_probs,
                                             x_bf, counts, tok, wts, slotmap);
  moe_gemm<<<NWG_G, 512, 0, stream>>>(x_bf, wT, eb, counts, tok, wts, y);
  combine_kernel<<<T_TOK, 256, 0, stream>>>(y, slotmap, out_final);
}